// Round 1
// baseline (8458.541 us; speedup 1.0000x reference)
//
#include <hip/hip_runtime.h>
#include <math.h>

// Problem constants
#define Vv 8000
#define Ee 256
#define Hh 256
#define Tt 4
#define Bb 64
#define Ss 512

#define EPROJ_PER_DIR (Vv * 1024)   // 8,192,000 floats per direction
#define WMAT_PER_DIR  (Ee * 1024)   // 262,144 floats per direction

// ---------------------------------------------------------------------------
// prep: repack weights.
//   WihP [dir][e][j']  j' = u*4+g  <-> gate-row g*256+u   (GEMM B-matrix)
//   Whh4 [dir][k][u][g] = Whh[g*256+u][k]                 (recurrent, float4/unit)
//   bP   [dir][j']     = b[g*256+u]
//   WlinP[dir][u][t]   = Wlin[t][dir*256+u]               (emission weights)
// ---------------------------------------------------------------------------
__global__ void prep_kernel(const float* __restrict__ Wih_f, const float* __restrict__ Whh_f,
                            const float* __restrict__ b_f,
                            const float* __restrict__ Wih_b, const float* __restrict__ Whh_b,
                            const float* __restrict__ b_b,
                            const float* __restrict__ Wlin,
                            float* __restrict__ WihP, float* __restrict__ Whh4,
                            float* __restrict__ bP, float* __restrict__ WlinP)
{
    int tid = blockIdx.x * blockDim.x + threadIdx.x;   // [0, 2*262144)
    int dir = tid >> 18;
    int r   = tid & 262143;
    int k   = r >> 10;        // 0..255 (e or k)
    int jp  = r & 1023;       // j'
    int u   = jp >> 2;
    int g   = jp & 3;
    int row = g * 256 + u;    // original gate row
    const float* Wih = dir ? Wih_b : Wih_f;
    const float* Whh = dir ? Whh_b : Whh_f;
    const float* bv  = dir ? b_b   : b_f;
    WihP[dir * WMAT_PER_DIR + k * 1024 + jp] = Wih[row * 256 + k];
    Whh4[dir * WMAT_PER_DIR + k * 1024 + jp] = Whh[row * 256 + k];
    if (r < 1024) {
        bP[dir * 1024 + jp] = bv[row];
        int uu = r >> 2, tt = r & 3;
        WlinP[dir * 1024 + r] = Wlin[tt * (2 * Hh) + dir * 256 + uu];
    }
}

// ---------------------------------------------------------------------------
// embproj GEMM: embproj[dir][v][j'] = sum_e emb[v][e]*WihP[dir][e][j'] + bP[dir][j']
// C(8000x1024) = A(8000x256) * B(256x1024); BM=64 BN=128 BK=16, 256 thr, 4x8 micro
// ---------------------------------------------------------------------------
#define BM 64
#define BN 128
#define BK 16
__global__ __launch_bounds__(256) void embproj_gemm(const float* __restrict__ emb,
                                                    const float* __restrict__ WihP,
                                                    const float* __restrict__ bP,
                                                    float* __restrict__ embproj)
{
    int dir = blockIdx.z;
    const float* Bmat = WihP + dir * WMAT_PER_DIR;
    float* C = embproj + (size_t)dir * EPROJ_PER_DIR;
    int m0 = blockIdx.x * BM;
    int n0 = blockIdx.y * BN;

    __shared__ float As[BK][BM];
    __shared__ float Bs[BK][BN];

    int t = threadIdx.x;
    int tm = (t & 15) * 4;
    int tn = (t >> 4) * 8;
    float acc[4][8];
    #pragma unroll
    for (int i = 0; i < 4; ++i)
        #pragma unroll
        for (int j = 0; j < 8; ++j) acc[i][j] = 0.f;

    for (int k0 = 0; k0 < Ee; k0 += BK) {
        {   // A tile 64x16
            int row = t >> 2, seg = t & 3;
            float4 a4 = *(const float4*)(&emb[(size_t)(m0 + row) * Ee + k0 + seg * 4]);
            As[seg * 4 + 0][row] = a4.x;
            As[seg * 4 + 1][row] = a4.y;
            As[seg * 4 + 2][row] = a4.z;
            As[seg * 4 + 3][row] = a4.w;
        }
        {   // B tile 16x128
            int kk = t >> 4, nn = (t & 15) * 8;
            float4 b0 = *(const float4*)(&Bmat[(size_t)(k0 + kk) * 1024 + n0 + nn]);
            float4 b1 = *(const float4*)(&Bmat[(size_t)(k0 + kk) * 1024 + n0 + nn + 4]);
            *(float4*)&Bs[kk][nn]     = b0;
            *(float4*)&Bs[kk][nn + 4] = b1;
        }
        __syncthreads();
        #pragma unroll
        for (int k = 0; k < BK; ++k) {
            float4 a  = *(const float4*)&As[k][tm];
            float4 b0 = *(const float4*)&Bs[k][tn];
            float4 b1 = *(const float4*)&Bs[k][tn + 4];
            float av[4] = {a.x, a.y, a.z, a.w};
            float bv[8] = {b0.x, b0.y, b0.z, b0.w, b1.x, b1.y, b1.z, b1.w};
            #pragma unroll
            for (int i = 0; i < 4; ++i)
                #pragma unroll
                for (int j = 0; j < 8; ++j)
                    acc[i][j] += av[i] * bv[j];
        }
        __syncthreads();
    }
    #pragma unroll
    for (int i = 0; i < 4; ++i) {
        int m = m0 + tm + i;
        #pragma unroll
        for (int j = 0; j < 8; j += 4) {
            float4 o;
            o.x = acc[i][j + 0] + bP[dir * 1024 + n0 + tn + j + 0];
            o.y = acc[i][j + 1] + bP[dir * 1024 + n0 + tn + j + 1];
            o.z = acc[i][j + 2] + bP[dir * 1024 + n0 + tn + j + 2];
            o.w = acc[i][j + 3] + bP[dir * 1024 + n0 + tn + j + 3];
            *(float4*)&C[(size_t)m * 1024 + n0 + tn + j] = o;
        }
    }
}

// ---------------------------------------------------------------------------
// LSTM recurrence, fused emission partials.
// grid: 64 blocks = dir(2) x batch-pair(32); block 512 = b2(2) x u(256)
// Each thread: hidden unit u of batch b; c in register; h via LDS.
// emis_dir[s][b][t] = sum_u h[u] * Wlin[t][dir*256+u]
// ---------------------------------------------------------------------------
__global__ __launch_bounds__(512) void lstm_kernel(const int* __restrict__ sentence,
                                                   const float* __restrict__ embproj,
                                                   const float* __restrict__ Whh4,
                                                   const float* __restrict__ WlinP,
                                                   float* __restrict__ emis_f,
                                                   float* __restrict__ emis_b)
{
    int blk = blockIdx.x;
    int dir = blk >> 5;
    int bpair = blk & 31;
    int t = threadIdx.x;
    int b2 = t >> 8;
    int u = t & 255;
    int b = bpair * 2 + b2;
    int wave = t >> 6;
    int lane = t & 63;

    const float* EP = embproj + (size_t)dir * EPROJ_PER_DIR;
    const float* W  = Whh4 + dir * WMAT_PER_DIR;
    float* emis = dir ? emis_b : emis_f;

    __shared__ float h_sh[2][256];
    __shared__ float4 wpart[8];

    h_sh[b2][u] = 0.f;
    float c = 0.f;
    float4 wl = *(const float4*)&WlinP[dir * 1024 + u * 4];
    const int* sent = sentence + b * Ss;
    __syncthreads();

    for (int s = 0; s < Ss; ++s) {
        int s_eff = dir ? (Ss - 1 - s) : s;
        int tok = sent[s_eff];
        float4 g4 = *(const float4*)&EP[(size_t)tok * 1024 + u * 4];

        const float* wp = &W[u * 4];
        const float4* h4 = (const float4*)h_sh[b2];
        #pragma unroll 2
        for (int k = 0; k < 256; k += 4) {
            float4 hv = h4[k >> 2];
            float4 w0 = *(const float4*)&wp[(k + 0) * 1024];
            float4 w1 = *(const float4*)&wp[(k + 1) * 1024];
            float4 w2 = *(const float4*)&wp[(k + 2) * 1024];
            float4 w3 = *(const float4*)&wp[(k + 3) * 1024];
            g4.x += hv.x * w0.x; g4.y += hv.x * w0.y; g4.z += hv.x * w0.z; g4.w += hv.x * w0.w;
            g4.x += hv.y * w1.x; g4.y += hv.y * w1.y; g4.z += hv.y * w1.z; g4.w += hv.y * w1.w;
            g4.x += hv.z * w2.x; g4.y += hv.z * w2.y; g4.z += hv.z * w2.z; g4.w += hv.z * w2.w;
            g4.x += hv.w * w3.x; g4.y += hv.w * w3.y; g4.z += hv.w * w3.z; g4.w += hv.w * w3.w;
        }
        float ig = 1.f / (1.f + expf(-g4.x));
        float fg = 1.f / (1.f + expf(-g4.y));
        float gg = tanhf(g4.z);
        float og = 1.f / (1.f + expf(-g4.w));
        c = fg * c + ig * gg;
        float hval = og * tanhf(c);

        __syncthreads();              // all reads of old h done
        h_sh[b2][u] = hval;
        // emission partial: reduce hval*wl over the 256 u's of this b2
        float4 cb;
        cb.x = hval * wl.x; cb.y = hval * wl.y; cb.z = hval * wl.z; cb.w = hval * wl.w;
        #pragma unroll
        for (int off = 32; off > 0; off >>= 1) {
            cb.x += __shfl_down(cb.x, off);
            cb.y += __shfl_down(cb.y, off);
            cb.z += __shfl_down(cb.z, off);
            cb.w += __shfl_down(cb.w, off);
        }
        if (lane == 0) wpart[wave] = cb;
        __syncthreads();              // new h + wpart visible
        if (u == 0) {
            float4 e0 = wpart[b2 * 4 + 0];
            float4 e1 = wpart[b2 * 4 + 1];
            float4 e2 = wpart[b2 * 4 + 2];
            float4 e3 = wpart[b2 * 4 + 3];
            float4 o;
            o.x = e0.x + e1.x + e2.x + e3.x;
            o.y = e0.y + e1.y + e2.y + e3.y;
            o.z = e0.z + e1.z + e2.z + e3.z;
            o.w = e0.w + e1.w + e2.w + e3.w;
            *(float4*)&emis[((size_t)s_eff * Bb + b) * 4] = o;
        }
    }
}

// ---------------------------------------------------------------------------
// CRF negative log-likelihood. 1 block x 64 threads (one per batch), wave-reduce loss.
// ---------------------------------------------------------------------------
__global__ void crf_kernel(const float* __restrict__ emis_f, const float* __restrict__ emis_b,
                           const float* __restrict__ blin,
                           const float* __restrict__ start_t, const float* __restrict__ end_t,
                           const float* __restrict__ trans,
                           const int* __restrict__ tags, float* __restrict__ out_loss)
{
    int b = threadIdx.x;
    float bl0 = blin[0], bl1 = blin[1], bl2 = blin[2], bl3 = blin[3];
    float tr[16];
    #pragma unroll
    for (int i = 0; i < 16; ++i) tr[i] = trans[i];

    float4 ef = *(const float4*)&emis_f[((size_t)0 * Bb + b) * 4];
    float4 eb = *(const float4*)&emis_b[((size_t)0 * Bb + b) * 4];
    float e[4] = {ef.x + eb.x + bl0, ef.y + eb.y + bl1, ef.z + eb.z + bl2, ef.w + eb.w + bl3};
    float alpha[4];
    #pragma unroll
    for (int j = 0; j < 4; ++j) alpha[j] = start_t[j] + e[j];
    int tag_prev = tags[b * Ss + 0];
    float num = start_t[tag_prev] + e[tag_prev];

    for (int s = 1; s < Ss; ++s) {
        ef = *(const float4*)&emis_f[((size_t)s * Bb + b) * 4];
        eb = *(const float4*)&emis_b[((size_t)s * Bb + b) * 4];
        e[0] = ef.x + eb.x + bl0; e[1] = ef.y + eb.y + bl1;
        e[2] = ef.z + eb.z + bl2; e[3] = ef.w + eb.w + bl3;
        float na[4];
        #pragma unroll
        for (int j = 0; j < 4; ++j) {
            float x0 = alpha[0] + tr[0 * 4 + j];
            float x1 = alpha[1] + tr[1 * 4 + j];
            float x2 = alpha[2] + tr[2 * 4 + j];
            float x3 = alpha[3] + tr[3 * 4 + j];
            float m = fmaxf(fmaxf(x0, x1), fmaxf(x2, x3));
            float sum = expf(x0 - m) + expf(x1 - m) + expf(x2 - m) + expf(x3 - m);
            na[j] = m + logf(sum) + e[j];
        }
        alpha[0] = na[0]; alpha[1] = na[1]; alpha[2] = na[2]; alpha[3] = na[3];
        int tg = tags[b * Ss + s];
        num += tr[tag_prev * 4 + tg] + e[tg];
        tag_prev = tg;
    }
    num += end_t[tag_prev];
    float x0 = alpha[0] + end_t[0];
    float x1 = alpha[1] + end_t[1];
    float x2 = alpha[2] + end_t[2];
    float x3 = alpha[3] + end_t[3];
    float m = fmaxf(fmaxf(x0, x1), fmaxf(x2, x3));
    float denom = m + logf(expf(x0 - m) + expf(x1 - m) + expf(x2 - m) + expf(x3 - m));
    float loss = -(num - denom);
    #pragma unroll
    for (int off = 32; off > 0; off >>= 1) loss += __shfl_down(loss, off);
    if (b == 0) out_loss[0] = loss;
}

// ---------------------------------------------------------------------------
// Viterbi. 1 block x 64 threads (one per batch). First-occurrence argmax to match jnp.
// ---------------------------------------------------------------------------
__global__ void viterbi_kernel(const float* __restrict__ emis_f, const float* __restrict__ emis_b,
                               const float* __restrict__ blin,
                               const float* __restrict__ start_t, const float* __restrict__ end_t,
                               const float* __restrict__ trans,
                               unsigned char* __restrict__ bp, float* __restrict__ out_tags)
{
    int b = threadIdx.x;
    float bl0 = blin[0], bl1 = blin[1], bl2 = blin[2], bl3 = blin[3];
    float tr[16];
    #pragma unroll
    for (int i = 0; i < 16; ++i) tr[i] = trans[i];

    float4 ef = *(const float4*)&emis_f[((size_t)0 * Bb + b) * 4];
    float4 eb = *(const float4*)&emis_b[((size_t)0 * Bb + b) * 4];
    float e[4] = {ef.x + eb.x + bl0, ef.y + eb.y + bl1, ef.z + eb.z + bl2, ef.w + eb.w + bl3};
    float score[4];
    #pragma unroll
    for (int j = 0; j < 4; ++j) score[j] = start_t[j] + e[j];

    for (int s = 1; s < Ss; ++s) {
        ef = *(const float4*)&emis_f[((size_t)s * Bb + b) * 4];
        eb = *(const float4*)&emis_b[((size_t)s * Bb + b) * 4];
        e[0] = ef.x + eb.x + bl0; e[1] = ef.y + eb.y + bl1;
        e[2] = ef.z + eb.z + bl2; e[3] = ef.w + eb.w + bl3;
        float ns[4];
        uchar4 bpj;
        unsigned char bi_arr[4];
        #pragma unroll
        for (int j = 0; j < 4; ++j) {
            float best = score[0] + tr[0 * 4 + j];
            int bi = 0;
            #pragma unroll
            for (int i = 1; i < 4; ++i) {
                float v = score[i] + tr[i * 4 + j];
                if (v > best) { best = v; bi = i; }
            }
            ns[j] = best + e[j];
            bi_arr[j] = (unsigned char)bi;
        }
        bpj.x = bi_arr[0]; bpj.y = bi_arr[1]; bpj.z = bi_arr[2]; bpj.w = bi_arr[3];
        *(uchar4*)&bp[((size_t)s * Bb + b) * 4] = bpj;
        score[0] = ns[0]; score[1] = ns[1]; score[2] = ns[2]; score[3] = ns[3];
    }
    float best = score[0] + end_t[0];
    int tag = 0;
    #pragma unroll
    for (int j = 1; j < 4; ++j) {
        float v = score[j] + end_t[j];
        if (v > best) { best = v; tag = j; }
    }
    out_tags[b * Ss + (Ss - 1)] = (float)tag;
    for (int s = Ss - 1; s >= 1; --s) {
        tag = bp[((size_t)s * Bb + b) * 4 + tag];
        out_tags[b * Ss + (s - 1)] = (float)tag;
    }
}

// ---------------------------------------------------------------------------
extern "C" void kernel_launch(void* const* d_in, const int* in_sizes, int n_in,
                              void* d_out, int out_size, void* d_ws, size_t ws_size,
                              hipStream_t stream)
{
    const int*   sentence = (const int*)d_in[0];
    const int*   tags     = (const int*)d_in[1];
    const float* emb      = (const float*)d_in[3];
    const float* Wih_f    = (const float*)d_in[4];
    const float* Whh_f    = (const float*)d_in[5];
    const float* b_f      = (const float*)d_in[6];
    const float* Wih_b    = (const float*)d_in[7];
    const float* Whh_b    = (const float*)d_in[8];
    const float* b_b      = (const float*)d_in[9];
    const float* Wlin     = (const float*)d_in[10];
    const float* blin     = (const float*)d_in[11];
    const float* start_t  = (const float*)d_in[12];
    const float* end_t    = (const float*)d_in[13];
    const float* trans    = (const float*)d_in[14];

    // workspace layout (floats)
    float* embproj = (float*)d_ws;                        // 2 * 8,192,000
    float* WihP    = embproj + 2 * EPROJ_PER_DIR;         // 2 * 262,144
    float* Whh4    = WihP + 2 * WMAT_PER_DIR;             // 2 * 262,144
    float* bP      = Whh4 + 2 * WMAT_PER_DIR;             // 2 * 1024
    float* WlinP   = bP + 2 * 1024;                       // 2 * 1024
    float* emis_f  = WlinP + 2 * 1024;                    // 512*64*4 = 131,072
    float* emis_b  = emis_f + Ss * Bb * 4;                // 131,072
    unsigned char* bp = (unsigned char*)(emis_b + Ss * Bb * 4);  // 512*64*4 bytes

    prep_kernel<<<2048, 256, 0, stream>>>(Wih_f, Whh_f, b_f, Wih_b, Whh_b, b_b, Wlin,
                                          WihP, Whh4, bP, WlinP);
    dim3 gg(Vv / BM, 1024 / BN, 2);
    embproj_gemm<<<gg, 256, 0, stream>>>(emb, WihP, bP, embproj);
    lstm_kernel<<<64, 512, 0, stream>>>(sentence, embproj, Whh4, WlinP, emis_f, emis_b);

    float* out = (float*)d_out;
    crf_kernel<<<1, 64, 0, stream>>>(emis_f, emis_b, blin, start_t, end_t, trans, tags,
                                     out + Bb * Ss);
    viterbi_kernel<<<1, 64, 0, stream>>>(emis_f, emis_b, blin, start_t, end_t, trans, bp, out);
}

// Round 2
// 4805.988 us; speedup vs baseline: 1.7600x; 1.7600x over previous
//
#include <hip/hip_runtime.h>
#include <math.h>

// Problem constants
#define Vv 8000
#define Ee 256
#define Hh 256
#define Tt 4
#define Bb 64
#define Ss 512

#define EPROJ_PER_DIR (Vv * 1024)   // 8,192,000 floats per direction
#define WMAT_PER_DIR  (Ee * 1024)   // 262,144 floats per direction

__device__ __forceinline__ float sigm(float x) { return 1.f / (1.f + expf(-x)); }

// ---------------------------------------------------------------------------
// prep: repack weights.
//   WihP [dir][e][j']  j' = u*4+g  <-> gate-row g*256+u   (GEMM B-matrix)
//   Whh4 [dir][k][u*4+g] = Whh[g*256+u][k]                (recurrent)
//   bP   [dir][j']     = b[g*256+u]
//   WlinP[dir][u*4+t]  = Wlin[t][dir*256+u]               (emission weights)
// ---------------------------------------------------------------------------
__global__ void prep_kernel(const float* __restrict__ Wih_f, const float* __restrict__ Whh_f,
                            const float* __restrict__ b_f,
                            const float* __restrict__ Wih_b, const float* __restrict__ Whh_b,
                            const float* __restrict__ b_b,
                            const float* __restrict__ Wlin,
                            float* __restrict__ WihP, float* __restrict__ Whh4,
                            float* __restrict__ bP, float* __restrict__ WlinP)
{
    int tid = blockIdx.x * blockDim.x + threadIdx.x;   // [0, 2*262144)
    int dir = tid >> 18;
    int r   = tid & 262143;
    int k   = r >> 10;        // 0..255 (e or k)
    int jp  = r & 1023;       // j'
    int u   = jp >> 2;
    int g   = jp & 3;
    int row = g * 256 + u;    // original gate row
    const float* Wih = dir ? Wih_b : Wih_f;
    const float* Whh = dir ? Whh_b : Whh_f;
    const float* bv  = dir ? b_b   : b_f;
    WihP[dir * WMAT_PER_DIR + k * 1024 + jp] = Wih[row * 256 + k];
    Whh4[dir * WMAT_PER_DIR + k * 1024 + jp] = Whh[row * 256 + k];
    if (r < 1024) {
        bP[dir * 1024 + jp] = bv[row];
        int uu = r >> 2, tt = r & 3;
        WlinP[dir * 1024 + r] = Wlin[tt * (2 * Hh) + dir * 256 + uu];
    }
}

// ---------------------------------------------------------------------------
// embproj GEMM: embproj[dir][v][j'] = sum_e emb[v][e]*WihP[dir][e][j'] + bP[dir][j']
// ---------------------------------------------------------------------------
#define BM 64
#define BN 128
#define BK 16
__global__ __launch_bounds__(256) void embproj_gemm(const float* __restrict__ emb,
                                                    const float* __restrict__ WihP,
                                                    const float* __restrict__ bP,
                                                    float* __restrict__ embproj)
{
    int dir = blockIdx.z;
    const float* Bmat = WihP + dir * WMAT_PER_DIR;
    float* C = embproj + (size_t)dir * EPROJ_PER_DIR;
    int m0 = blockIdx.x * BM;
    int n0 = blockIdx.y * BN;

    __shared__ float As[BK][BM];
    __shared__ float Bs[BK][BN];

    int t = threadIdx.x;
    int tm = (t & 15) * 4;
    int tn = (t >> 4) * 8;
    float acc[4][8];
    #pragma unroll
    for (int i = 0; i < 4; ++i)
        #pragma unroll
        for (int j = 0; j < 8; ++j) acc[i][j] = 0.f;

    for (int k0 = 0; k0 < Ee; k0 += BK) {
        {   // A tile 64x16
            int row = t >> 2, seg = t & 3;
            float4 a4 = *(const float4*)(&emb[(size_t)(m0 + row) * Ee + k0 + seg * 4]);
            As[seg * 4 + 0][row] = a4.x;
            As[seg * 4 + 1][row] = a4.y;
            As[seg * 4 + 2][row] = a4.z;
            As[seg * 4 + 3][row] = a4.w;
        }
        {   // B tile 16x128
            int kk = t >> 4, nn = (t & 15) * 8;
            float4 b0 = *(const float4*)(&Bmat[(size_t)(k0 + kk) * 1024 + n0 + nn]);
            float4 b1 = *(const float4*)(&Bmat[(size_t)(k0 + kk) * 1024 + n0 + nn + 4]);
            *(float4*)&Bs[kk][nn]     = b0;
            *(float4*)&Bs[kk][nn + 4] = b1;
        }
        __syncthreads();
        #pragma unroll
        for (int k = 0; k < BK; ++k) {
            float4 a  = *(const float4*)&As[k][tm];
            float4 b0 = *(const float4*)&Bs[k][tn];
            float4 b1 = *(const float4*)&Bs[k][tn + 4];
            float av[4] = {a.x, a.y, a.z, a.w};
            float bv[8] = {b0.x, b0.y, b0.z, b0.w, b1.x, b1.y, b1.z, b1.w};
            #pragma unroll
            for (int i = 0; i < 4; ++i)
                #pragma unroll
                for (int j = 0; j < 8; ++j)
                    acc[i][j] += av[i] * bv[j];
        }
        __syncthreads();
    }
    #pragma unroll
    for (int i = 0; i < 4; ++i) {
        int m = m0 + tm + i;
        #pragma unroll
        for (int j = 0; j < 8; j += 4) {
            float4 o;
            o.x = acc[i][j + 0] + bP[dir * 1024 + n0 + tn + j + 0];
            o.y = acc[i][j + 1] + bP[dir * 1024 + n0 + tn + j + 1];
            o.z = acc[i][j + 2] + bP[dir * 1024 + n0 + tn + j + 2];
            o.w = acc[i][j + 3] + bP[dir * 1024 + n0 + tn + j + 3];
            *(float4*)&C[(size_t)m * 1024 + n0 + tn + j] = o;
        }
    }
}

// ---------------------------------------------------------------------------
// LSTM recurrence, team-of-4 WGs per (dir, batch-pair), weights VGPR-resident.
// grid: 256 cooperative blocks x 512 threads.
//   block -> (team, us): xcd-swizzled so a team's 4 members share an XCD slot set.
//   team = (dir, bg);  WG owns hidden units u in [us*64, us*64+64).
//   thread t: u_loc = t>>3 (unit), ks = t&7 (k-slice of 32).
//   Persistent weights: w4[32] = Whh'[k = ks*32+kk][ (u0+u_loc)*4 + 0..3 ].
//   Per step: load h(s-1) (2KB) from global -> swizzled LDS; 256 reg FMAs;
//   shfl-reduce over ks; activation on ks==0 lanes (c in regs); publish h(s)
//   + release flag. Emission tag 'us' fused (reduction over full h in LDS).
// ---------------------------------------------------------------------------
__global__ __launch_bounds__(512, 2) void lstm_team_kernel(
    const int* __restrict__ sentence,
    const float* __restrict__ embproj,
    const float* __restrict__ Whh4,
    const float* __restrict__ WlinP,
    float* __restrict__ h_glob,
    int* __restrict__ flags,
    float* __restrict__ emis_f,
    float* __restrict__ emis_b)
{
    const int bx = blockIdx.x;
    const int xcd = bx & 7, slot = bx >> 3;
    const int team = xcd * 8 + (slot & 7);   // 0..63
    const int us   = slot >> 3;              // 0..3
    const int dir  = team >> 5;
    const int bg   = team & 31;
    const int u0   = us * 64;
    const int t    = threadIdx.x;
    const int u_loc = t >> 3;     // 0..63
    const int ks    = t & 7;      // 0..7
    const int lb2 = t >> 8, lk = t & 255;    // loader mapping
    const int eb2 = t >> 8, eu = t & 255;    // emission mapping

    __shared__ float h_sh_raw[512];   // [b2][256] f32, XOR-swizzled bytes
    __shared__ float red_sh[8];
    char* hbase = (char*)h_sh_raw;

    // persistent weights -> 128 VGPRs
    float4 w4[32];
    {
        const float* Wb = Whh4 + (size_t)dir * WMAT_PER_DIR
                        + (size_t)(ks * 32) * 1024 + (size_t)(u0 + u_loc) * 4;
        #pragma unroll
        for (int kk = 0; kk < 32; ++kk)
            w4[kk] = *(const float4*)(Wb + (size_t)kk * 1024);
    }
    const float wl_u = WlinP[dir * 1024 + eu * 4 + us];

    // swizzle: byte' = byte ^ (((byte>>7)&7)<<4)  (spreads k-slices across bank quads)
    const int st_byte = ((lb2 << 10) + (lk << 2)) ^ (((lk >> 5) & 7) << 4);
    const int em_byte = ((eb2 << 10) + (eu << 2)) ^ (((eu >> 5) & 7) << 4);
    const int klb0 = (ks << 7);
    const int klb1 = 1024 + (ks << 7);
    const int klx  = (ks << 4);

    const bool is_act = (ks == 0);
    const int fl_base = team * 4;
    const int flag_self = fl_base + us;
    float* Hbase = h_glob + (size_t)team * 1024;   // [parity][b2][256]
    const float* EP = embproj + (size_t)dir * EPROJ_PER_DIR;
    float* emis = dir ? emis_b : emis_f;
    const int b0 = bg * 2;
    const int* sentA = sentence + (size_t)b0 * Ss;
    const int* sentB = sentence + (size_t)(b0 + 1) * Ss;

    float c0 = 0.f, c1 = 0.f;
    long budget = 50000000;   // bounded spin: wrong-answer instead of hang on bug

    for (int s = 0; s < Ss; ++s) {
        const int pos = dir ? (Ss - 1 - s) : s;
        float4 ep0, ep1;
        if (is_act) {   // deep prefetch of gate preactivation rows (L3-resident table)
            const int tok0 = sentA[pos], tok1 = sentB[pos];
            ep0 = *(const float4*)(EP + (size_t)tok0 * 1024 + (u0 + u_loc) * 4);
            ep1 = *(const float4*)(EP + (size_t)tok1 * 1024 + (u0 + u_loc) * 4);
        }
        if (s > 0) {
            if (t < 3) {
                const int peer = fl_base + ((us + 1 + t) & 3);
                while (__hip_atomic_load(&flags[peer], __ATOMIC_ACQUIRE,
                                         __HIP_MEMORY_SCOPE_AGENT) < s) {
                    if (--budget < 0) break;
                }
            }
            __syncthreads();
            const float* src = Hbase + ((s - 1) & 1) * 512;
            *(float*)(hbase + st_byte) = src[(lb2 << 8) + lk];
        } else {
            *(float*)(hbase + st_byte) = 0.f;
        }
        __syncthreads();

        // fused emission for step s-1 (tag = us), over full h in LDS
        if (s > 0) {
            float ev = (*(const float*)(hbase + em_byte)) * wl_u;
            #pragma unroll
            for (int off = 32; off > 0; off >>= 1) ev += __shfl_down(ev, off);
            if ((t & 63) == 0) red_sh[t >> 6] = ev;
        }

        // gate FMAs: 2 batches x 4 gates over this thread's 32 k's (reg weights)
        float4 a0 = make_float4(0.f,0.f,0.f,0.f), a1 = make_float4(0.f,0.f,0.f,0.f);
        #pragma unroll
        for (int k4 = 0; k4 < 8; ++k4) {
            const float4 h0 = *(const float4*)(hbase + ((klb0 + (k4 << 4)) ^ klx));
            const float4 h1 = *(const float4*)(hbase + ((klb1 + (k4 << 4)) ^ klx));
            const float4 wA = w4[k4*4+0], wB = w4[k4*4+1], wC = w4[k4*4+2], wD = w4[k4*4+3];
            a0.x += h0.x*wA.x; a0.y += h0.x*wA.y; a0.z += h0.x*wA.z; a0.w += h0.x*wA.w;
            a0.x += h0.y*wB.x; a0.y += h0.y*wB.y; a0.z += h0.y*wB.z; a0.w += h0.y*wB.w;
            a0.x += h0.z*wC.x; a0.y += h0.z*wC.y; a0.z += h0.z*wC.z; a0.w += h0.z*wC.w;
            a0.x += h0.w*wD.x; a0.y += h0.w*wD.y; a0.z += h0.w*wD.z; a0.w += h0.w*wD.w;
            a1.x += h1.x*wA.x; a1.y += h1.x*wA.y; a1.z += h1.x*wA.z; a1.w += h1.x*wA.w;
            a1.x += h1.y*wB.x; a1.y += h1.y*wB.y; a1.z += h1.y*wB.z; a1.w += h1.y*wB.w;
            a1.x += h1.z*wC.x; a1.y += h1.z*wC.y; a1.z += h1.z*wC.z; a1.w += h1.z*wC.w;
            a1.x += h1.w*wD.x; a1.y += h1.w*wD.y; a1.z += h1.w*wD.z; a1.w += h1.w*wD.w;
        }
        // reduce over ks within each aligned 8-lane group
        #pragma unroll
        for (int off = 4; off > 0; off >>= 1) {
            a0.x += __shfl_down(a0.x, off); a0.y += __shfl_down(a0.y, off);
            a0.z += __shfl_down(a0.z, off); a0.w += __shfl_down(a0.w, off);
            a1.x += __shfl_down(a1.x, off); a1.y += __shfl_down(a1.y, off);
            a1.z += __shfl_down(a1.z, off); a1.w += __shfl_down(a1.w, off);
        }
        __syncthreads();   // red_sh visible
        if (s > 0 && t < 2) {
            const float r = red_sh[t*4+0] + red_sh[t*4+1] + red_sh[t*4+2] + red_sh[t*4+3];
            const int pm1 = dir ? (Ss - s) : (s - 1);
            emis[((size_t)pm1 * Bb + (b0 + t)) * 4 + us] = r;
        }
        if (is_act) {
            const float i0 = a0.x + ep0.x, f0 = a0.y + ep0.y, g0 = a0.z + ep0.z, o0 = a0.w + ep0.w;
            const float i1 = a1.x + ep1.x, f1 = a1.y + ep1.y, g1 = a1.z + ep1.z, o1 = a1.w + ep1.w;
            c0 = sigm(f0) * c0 + sigm(i0) * tanhf(g0);
            c1 = sigm(f1) * c1 + sigm(i1) * tanhf(g1);
            float* dst = Hbase + (s & 1) * 512;
            dst[u0 + u_loc]       = sigm(o0) * tanhf(c0);
            dst[256 + u0 + u_loc] = sigm(o1) * tanhf(c1);
        }
        __syncthreads();   // drains h stores (per-wave vmcnt before barrier)
        if (t == 0)
            __hip_atomic_store(&flags[flag_self], s + 1, __ATOMIC_RELEASE,
                               __HIP_MEMORY_SCOPE_AGENT);
    }

    // final emission for sigma = Ss-1
    if (t < 3) {
        const int peer = fl_base + ((us + 1 + t) & 3);
        while (__hip_atomic_load(&flags[peer], __ATOMIC_ACQUIRE,
                                 __HIP_MEMORY_SCOPE_AGENT) < Ss) {
            if (--budget < 0) break;
        }
    }
    __syncthreads();
    {
        const float* src = Hbase + ((Ss - 1) & 1) * 512;
        *(float*)(hbase + st_byte) = src[(lb2 << 8) + lk];
    }
    __syncthreads();
    {
        float ev = (*(const float*)(hbase + em_byte)) * wl_u;
        #pragma unroll
        for (int off = 32; off > 0; off >>= 1) ev += __shfl_down(ev, off);
        if ((t & 63) == 0) red_sh[t >> 6] = ev;
    }
    __syncthreads();
    if (t < 2) {
        const float r = red_sh[t*4+0] + red_sh[t*4+1] + red_sh[t*4+2] + red_sh[t*4+3];
        const int pm1 = dir ? 0 : (Ss - 1);
        emis[((size_t)pm1 * Bb + (b0 + t)) * 4 + us] = r;
    }
}

// ---------------------------------------------------------------------------
// Fused CRF + Viterbi tail. grid 8 x 64 threads.
//   blocks 0-3: Viterbi for 16 batches each, thread = (b_loc, tag j), bp in LDS.
//   blocks 4-7: CRF llh for 16 batches each: lse scan lane-parallel over tags,
//               tag-score (num) parallel over 4 s-chunks, loss via atomicAdd.
// ---------------------------------------------------------------------------
__global__ __launch_bounds__(64) void tail_kernel(
    const float* __restrict__ emis_f, const float* __restrict__ emis_b,
    const float* __restrict__ blin, const float* __restrict__ start_t,
    const float* __restrict__ end_t, const float* __restrict__ trans,
    const int* __restrict__ tags, float* __restrict__ out_tags,
    float* __restrict__ out_loss)
{
    const int blk = blockIdx.x;
    const int t = threadIdx.x;
    const int b_loc = t >> 2, j = t & 3;
    const int base = t & ~3;

    if (blk < 4) {
        __shared__ unsigned char bp_sh[16][513][4];   // +1 row pad: bank spread
        __shared__ unsigned char tag_sh[16][520];
        const int b = blk * 16 + b_loc;
        const float trj0 = trans[0*4+j], trj1 = trans[1*4+j],
                    trj2 = trans[2*4+j], trj3 = trans[3*4+j];
        const float blj = blin[j];
        float score = start_t[j] + emis_f[(size_t)b*4 + j] + emis_b[(size_t)b*4 + j] + blj;
        for (int s = 1; s < Ss; ++s) {
            const float e = emis_f[((size_t)s*Bb + b)*4 + j]
                          + emis_b[((size_t)s*Bb + b)*4 + j] + blj;
            const float s0 = __shfl(score, base+0), s1 = __shfl(score, base+1),
                        s2 = __shfl(score, base+2), s3 = __shfl(score, base+3);
            float best = s0 + trj0; int bi = 0;
            float v = s1 + trj1; if (v > best) { best = v; bi = 1; }
            v = s2 + trj2; if (v > best) { best = v; bi = 2; }
            v = s3 + trj3; if (v > best) { best = v; bi = 3; }
            score = best + e;
            bp_sh[b_loc][s][j] = (unsigned char)bi;
        }
        const float fv = score + end_t[j];
        const float f0 = __shfl(fv, base+0), f1 = __shfl(fv, base+1),
                    f2 = __shfl(fv, base+2), f3 = __shfl(fv, base+3);
        __syncthreads();
        if (j == 0) {   // backtrack (first-occurrence argmax ties, like jnp)
            float best = f0; int tag = 0;
            if (f1 > best) { best = f1; tag = 1; }
            if (f2 > best) { best = f2; tag = 2; }
            if (f3 > best) { best = f3; tag = 3; }
            tag_sh[b_loc][Ss-1] = (unsigned char)tag;
            for (int s = Ss - 1; s >= 1; --s) {
                tag = bp_sh[b_loc][s][tag];
                tag_sh[b_loc][s-1] = (unsigned char)tag;
            }
        }
        __syncthreads();
        for (int idx = t; idx < 16 * Ss; idx += 64) {
            const int bl = idx >> 9, s = idx & (Ss - 1);
            out_tags[(size_t)(blk*16 + bl) * Ss + s] = (float)tag_sh[bl][s];
        }
    } else {
        const int b = (blk - 4) * 16 + b_loc;
        const float trj0 = trans[0*4+j], trj1 = trans[1*4+j],
                    trj2 = trans[2*4+j], trj3 = trans[3*4+j];
        const float blj = blin[j];
        float alpha = start_t[j] + emis_f[(size_t)b*4 + j] + emis_b[(size_t)b*4 + j] + blj;
        for (int s = 1; s < Ss; ++s) {
            const float e = emis_f[((size_t)s*Bb + b)*4 + j]
                          + emis_b[((size_t)s*Bb + b)*4 + j] + blj;
            const float a0 = __shfl(alpha, base+0), a1 = __shfl(alpha, base+1),
                        a2 = __shfl(alpha, base+2), a3 = __shfl(alpha, base+3);
            const float x0 = a0 + trj0, x1 = a1 + trj1, x2 = a2 + trj2, x3 = a3 + trj3;
            const float m = fmaxf(fmaxf(x0, x1), fmaxf(x2, x3));
            alpha = m + logf(expf(x0-m) + expf(x1-m) + expf(x2-m) + expf(x3-m)) + e;
        }
        const float dv = alpha + end_t[j];
        const float d0 = __shfl(dv, base+0), d1 = __shfl(dv, base+1),
                    d2 = __shfl(dv, base+2), d3 = __shfl(dv, base+3);
        const float dm = fmaxf(fmaxf(d0, d1), fmaxf(d2, d3));
        const float denom = dm + logf(expf(d0-dm) + expf(d1-dm) + expf(d2-dm) + expf(d3-dm));

        // tag-path score: thread j sums s in [j*128, j*128+128)
        const int lo = j * 128, hi = lo + 128;
        float num = 0.f;
        int tprev = (lo > 0) ? tags[(size_t)b*Ss + lo - 1] : 0;
        if (j == 0) num += start_t[tags[(size_t)b*Ss]];
        if (j == 3) num += end_t[tags[(size_t)b*Ss + Ss - 1]];
        #pragma unroll 4
        for (int s = lo; s < hi; ++s) {
            const int tg = tags[(size_t)b*Ss + s];
            num += emis_f[((size_t)s*Bb + b)*4 + tg]
                 + emis_b[((size_t)s*Bb + b)*4 + tg] + blin[tg];
            if (s > 0) num += trans[tprev*4 + tg];
            tprev = tg;
        }
        num += __shfl_xor(num, 1);
        num += __shfl_xor(num, 2);
        float lb = (j == 0) ? (denom - num) : 0.f;
        #pragma unroll
        for (int off = 32; off > 0; off >>= 1) lb += __shfl_down(lb, off);
        if (t == 0) atomicAdd(out_loss, lb);
    }
}

// ---------------------------------------------------------------------------
extern "C" void kernel_launch(void* const* d_in, const int* in_sizes, int n_in,
                              void* d_out, int out_size, void* d_ws, size_t ws_size,
                              hipStream_t stream)
{
    const int*   sentence = (const int*)d_in[0];
    const int*   tags     = (const int*)d_in[1];
    const float* emb      = (const float*)d_in[3];
    const float* Wih_f    = (const float*)d_in[4];
    const float* Whh_f    = (const float*)d_in[5];
    const float* b_f      = (const float*)d_in[6];
    const float* Wih_b    = (const float*)d_in[7];
    const float* Whh_b    = (const float*)d_in[8];
    const float* b_b      = (const float*)d_in[9];
    const float* Wlin     = (const float*)d_in[10];
    const float* blin     = (const float*)d_in[11];
    const float* start_t  = (const float*)d_in[12];
    const float* end_t    = (const float*)d_in[13];
    const float* trans    = (const float*)d_in[14];

    // workspace layout (floats)
    float* embproj = (float*)d_ws;                        // 2 * 8,192,000
    float* WihP    = embproj + 2 * EPROJ_PER_DIR;         // 2 * 262,144 (reused below)
    float* Whh4    = WihP + 2 * WMAT_PER_DIR;             // 2 * 262,144
    float* bP      = Whh4 + 2 * WMAT_PER_DIR;             // 2 * 1024
    float* WlinP   = bP + 2 * 1024;                       // 2 * 1024
    float* emis_f  = WlinP + 2 * 1024;                    // 512*64*4
    float* emis_b  = emis_f + Ss * Bb * 4;                // 512*64*4

    // WihP region is dead after the GEMM -> reuse for sync flags + h exchange
    int*   flags  = (int*)WihP;                           // 256 ints
    float* h_glob = WihP + 1024;                          // 64 teams * 1024 floats

    prep_kernel<<<2048, 256, 0, stream>>>(Wih_f, Whh_f, b_f, Wih_b, Whh_b, b_b, Wlin,
                                          WihP, Whh4, bP, WlinP);
    dim3 gg(Vv / BM, 1024 / BN, 2);
    embproj_gemm<<<gg, 256, 0, stream>>>(emb, WihP, bP, embproj);

    hipMemsetAsync(flags, 0, 256 * sizeof(int), stream);

    const int* k_sent = sentence;
    const float* k_ep = embproj;
    const float* k_whh = Whh4;
    const float* k_wlin = WlinP;
    float* k_h = h_glob;
    int* k_fl = flags;
    float* k_ef = emis_f;
    float* k_eb = emis_b;
    void* args[] = { (void*)&k_sent, (void*)&k_ep, (void*)&k_whh, (void*)&k_wlin,
                     (void*)&k_h, (void*)&k_fl, (void*)&k_ef, (void*)&k_eb };
    hipLaunchCooperativeKernel((const void*)lstm_team_kernel, dim3(256), dim3(512),
                               args, 0, stream);

    float* out = (float*)d_out;
    float* out_loss = out + Bb * Ss;
    hipMemsetAsync(out_loss, 0, sizeof(float), stream);
    tail_kernel<<<8, 64, 0, stream>>>(emis_f, emis_b, blin, start_t, end_t, trans,
                                      tags, out, out_loss);
}